// Round 1
// baseline (246.074 us; speedup 1.0000x reference)
//
#include <hip/hip_runtime.h>
#include <cstdint>
#include <cstddef>

// ---------------------------------------------------------------------------
// CosineDistance via exact int8 reconstruction:
//   ref's 9 bit-slice GEMMs == qx (int8) @ qw^T (int8), dequant, 1 - cos.
// ---------------------------------------------------------------------------

#define D_COLS 1024
#define M_ROWS 4096   // x rows
#define N_ROWS 8192   // weight rows

using i32x4 = __attribute__((ext_vector_type(4))) int;

__device__ __forceinline__ void gload_lds16(const void* g, void* lds) {
  __builtin_amdgcn_global_load_lds(
      (const __attribute__((address_space(1))) uint32_t*)g,
      (__attribute__((address_space(3))) uint32_t*)lds, 16, 0, 0);
}

// One block per row: sum of squares + row max|a|, then invnorm and
// atomicMax of max|a|*invnorm into the global scale (float bits, >=0).
__global__ __launch_bounds__(256) void rownorm_kernel(
    const float* __restrict__ a, float* __restrict__ invnorm,
    unsigned int* __restrict__ scale_bits) {
  const int row = blockIdx.x;
  const float4 v = ((const float4*)(a + (size_t)row * D_COLS))[threadIdx.x];
  float ss = v.x * v.x + v.y * v.y + v.z * v.z + v.w * v.w;
  float mx = fmaxf(fmaxf(fabsf(v.x), fabsf(v.y)), fmaxf(fabsf(v.z), fabsf(v.w)));
#pragma unroll
  for (int off = 32; off; off >>= 1) {
    ss += __shfl_down(ss, off, 64);
    mx = fmaxf(mx, __shfl_down(mx, off, 64));
  }
  __shared__ float s_ss[4], s_mx[4];
  const int wave = threadIdx.x >> 6, lane = threadIdx.x & 63;
  if (lane == 0) { s_ss[wave] = ss; s_mx[wave] = mx; }
  __syncthreads();
  if (threadIdx.x == 0) {
    float tss = (s_ss[0] + s_ss[1]) + (s_ss[2] + s_ss[3]);
    float tmx = fmaxf(fmaxf(s_mx[0], s_mx[1]), fmaxf(s_mx[2], s_mx[3]));
    float inv = 1.0f / fmaxf(sqrtf(tss), 1e-12f);
    invnorm[row] = inv;
    atomicMax(scale_bits, __float_as_uint(tmx * inv));
  }
}

// Quantize: q = rint(a * invnorm_row * 127/scale) -> int8, packed 4/thread.
__global__ __launch_bounds__(256) void quant_kernel(
    const float* __restrict__ a, const float* __restrict__ invnorm,
    const float* __restrict__ scale, unsigned int* __restrict__ qout) {
  const int idx = blockIdx.x * 256 + threadIdx.x;     // one float4 per thread
  const float s = 127.0f / scale[0];
  const float4 v = ((const float4*)a)[idx];
  const int row = idx >> 8;                           // 256 float4 per row
  const float f = invnorm[row] * s;
  int q0 = (int)rintf(v.x * f);
  int q1 = (int)rintf(v.y * f);
  int q2 = (int)rintf(v.z * f);
  int q3 = (int)rintf(v.w * f);
  qout[idx] = (unsigned)(q0 & 0xff) | ((unsigned)(q1 & 0xff) << 8) |
              ((unsigned)(q2 & 0xff) << 16) | ((unsigned)(q3 & 0xff) << 24);
}

// int8 GEMM: out[m,n] = 1 - (qx[m,:] . qw[n,:]) * cs
// 128x128 tile, 4 waves (2x2 of 64x64), BK=64, mfma_i32_16x16x64_i8.
// LDS tiles laid out [ko][row][16B] so ds_read_b128 fragments are
// conflict-free and global_load_lds destinations are linear.
__global__ __launch_bounds__(256) void gemm_i8_kernel(
    const char* __restrict__ qx, const char* __restrict__ qw,
    const float* __restrict__ sx, const float* __restrict__ sw,
    float* __restrict__ out) {
  __shared__ char As[8192];
  __shared__ char Bs[8192];
  const int t = threadIdx.x;
  const int wave = t >> 6, lane = t & 63;
  const int wr = wave >> 1, wc = wave & 1;
  const int rowBase = blockIdx.y * 128;
  const int colBase = blockIdx.x * 128;

  i32x4 acc[4][4] = {};

  const int ko = lane >> 4, rl = lane & 15;

#pragma unroll 1
  for (int ks = 0; ks < 16; ++ks) {
    __syncthreads();  // previous compute done; safe to overwrite tiles
    const int k0 = ks * 64;
#pragma unroll
    for (int is = 0; is < 2; ++is) {
      const int ci = is * 256 + t;          // chunk index 0..511
      const int cko = ci >> 7, cr = ci & 127;
      const size_t goffA = (size_t)(rowBase + cr) * D_COLS + k0 + cko * 16;
      const size_t goffB = (size_t)(colBase + cr) * D_COLS + k0 + cko * 16;
      char* ldsA = As + is * 4096 + wave * 1024;  // wave-uniform base
      char* ldsB = Bs + is * 4096 + wave * 1024;
      gload_lds16(qx + goffA, ldsA);
      gload_lds16(qw + goffB, ldsB);
    }
    __syncthreads();  // drains vmcnt before barrier => tiles ready

    i32x4 af[4], bf[4];
#pragma unroll
    for (int m = 0; m < 4; ++m)
      af[m] = *(const i32x4*)(As + ko * 2048 + (wr * 64 + m * 16 + rl) * 16);
#pragma unroll
    for (int n = 0; n < 4; ++n)
      bf[n] = *(const i32x4*)(Bs + ko * 2048 + (wc * 64 + n * 16 + rl) * 16);
#pragma unroll
    for (int m = 0; m < 4; ++m)
#pragma unroll
      for (int n = 0; n < 4; ++n)
        acc[m][n] = __builtin_amdgcn_mfma_i32_16x16x64_i8(af[m], bf[n], acc[m][n], 0, 0, 0);
  }

  const float cs = sx[0] * sw[0] * (1.0f / 16129.0f);  // (sx/127)*(sw/127)
#pragma unroll
  for (int m = 0; m < 4; ++m) {
    const int row = rowBase + wr * 64 + m * 16 + (lane >> 4) * 4;
#pragma unroll
    for (int n = 0; n < 4; ++n) {
      const int col = colBase + wc * 64 + n * 16 + (lane & 15);
#pragma unroll
      for (int j = 0; j < 4; ++j)
        out[(size_t)(row + j) * N_ROWS + col] = 1.0f - (float)acc[m][n][j] * cs;
    }
  }
}

extern "C" void kernel_launch(void* const* d_in, const int* in_sizes, int n_in,
                              void* d_out, int out_size, void* d_ws, size_t ws_size,
                              hipStream_t stream) {
  const float* x = (const float*)d_in[0];   // [4096, 1024]
  const float* w = (const float*)d_in[1];   // [8192, 1024]
  float* out = (float*)d_out;               // [4096, 8192]

  char* ws = (char*)d_ws;
  char* qx = ws;                                        // 4 MB int8
  char* qw = ws + (size_t)M_ROWS * D_COLS;              // 8 MB int8
  float* invnorm_x = (float*)(ws + (size_t)(M_ROWS + N_ROWS) * D_COLS);
  float* invnorm_w = invnorm_x + M_ROWS;
  float* scales = invnorm_w + N_ROWS;                   // [0]=sx_max, [1]=sw_max

  // zero the two scale slots (atomicMax targets)
  hipMemsetAsync(scales, 0, 2 * sizeof(float), stream);

  rownorm_kernel<<<M_ROWS, 256, 0, stream>>>(x, invnorm_x, (unsigned int*)&scales[0]);
  rownorm_kernel<<<N_ROWS, 256, 0, stream>>>(w, invnorm_w, (unsigned int*)&scales[1]);

  quant_kernel<<<M_ROWS * (D_COLS / 4) / 256, 256, 0, stream>>>(
      x, invnorm_x, &scales[0], (unsigned int*)qx);
  quant_kernel<<<N_ROWS * (D_COLS / 4) / 256, 256, 0, stream>>>(
      w, invnorm_w, &scales[1], (unsigned int*)qw);

  dim3 grid(N_ROWS / 128, M_ROWS / 128);  // (64, 32)
  gemm_i8_kernel<<<grid, 256, 0, stream>>>(qx, qw, &scales[0], &scales[1], out);
}

// Round 2
// 108.357 us; speedup vs baseline: 2.2710x; 2.2710x over previous
//
#include <hip/hip_runtime.h>
#include <cstdint>
#include <cstddef>

// ---------------------------------------------------------------------------
// CosineDistance via exact int8 reconstruction:
//   ref's 9 bit-slice GEMMs == qx (int8) @ qw^T (int8), dequant, 1 - cos.
// R2: removed single-address atomicMax serialization (99us @ 2% BW) --
//     per-row maxes to arrays + single-block reduce.
// ---------------------------------------------------------------------------

#define D_COLS 1024
#define M_ROWS 4096   // x rows
#define N_ROWS 8192   // weight rows

using i32x4 = __attribute__((ext_vector_type(4))) int;

__device__ __forceinline__ void gload_lds16(const void* g, void* lds) {
  __builtin_amdgcn_global_load_lds(
      (const __attribute__((address_space(1))) uint32_t*)g,
      (__attribute__((address_space(3))) uint32_t*)lds, 16, 0, 0);
}

// One block per row (x rows 0..4095, w rows 4096..12287):
// invnorm[row] = 1/||row||, rmax[row] = max|row| * invnorm. No atomics.
__global__ __launch_bounds__(256) void rownorm_kernel(
    const float* __restrict__ x, const float* __restrict__ w,
    float* __restrict__ invnorm, float* __restrict__ rmax) {
  const int row = blockIdx.x;
  const float* a = (row < M_ROWS) ? x + (size_t)row * D_COLS
                                  : w + (size_t)(row - M_ROWS) * D_COLS;
  const float4 v = ((const float4*)a)[threadIdx.x];
  float ss = v.x * v.x + v.y * v.y + v.z * v.z + v.w * v.w;
  float mx = fmaxf(fmaxf(fabsf(v.x), fabsf(v.y)), fmaxf(fabsf(v.z), fabsf(v.w)));
#pragma unroll
  for (int off = 32; off; off >>= 1) {
    ss += __shfl_down(ss, off, 64);
    mx = fmaxf(mx, __shfl_down(mx, off, 64));
  }
  __shared__ float s_ss[4], s_mx[4];
  const int wave = threadIdx.x >> 6, lane = threadIdx.x & 63;
  if (lane == 0) { s_ss[wave] = ss; s_mx[wave] = mx; }
  __syncthreads();
  if (threadIdx.x == 0) {
    float tss = (s_ss[0] + s_ss[1]) + (s_ss[2] + s_ss[3]);
    float tmx = fmaxf(fmaxf(s_mx[0], s_mx[1]), fmaxf(s_mx[2], s_mx[3]));
    float inv = 1.0f / fmaxf(sqrtf(tss), 1e-12f);
    invnorm[row] = inv;
    rmax[row] = tmx * inv;
  }
}

// Single block: scales[0] = max(rmax[0:4096]), scales[1] = max(rmax[4096:12288])
__global__ __launch_bounds__(1024) void scale_reduce_kernel(
    const float* __restrict__ rmax, float* __restrict__ scales) {
  const int t = threadIdx.x;
  float mx = 0.f, mw = 0.f;
  for (int i = t; i < M_ROWS; i += 1024) mx = fmaxf(mx, rmax[i]);
  for (int i = t; i < N_ROWS; i += 1024) mw = fmaxf(mw, rmax[M_ROWS + i]);
#pragma unroll
  for (int off = 32; off; off >>= 1) {
    mx = fmaxf(mx, __shfl_down(mx, off, 64));
    mw = fmaxf(mw, __shfl_down(mw, off, 64));
  }
  __shared__ float smx[16], smw[16];
  const int wave = t >> 6, lane = t & 63;
  if (lane == 0) { smx[wave] = mx; smw[wave] = mw; }
  __syncthreads();
  if (t == 0) {
    float a = 0.f, b = 0.f;
#pragma unroll
    for (int i = 0; i < 16; ++i) { a = fmaxf(a, smx[i]); b = fmaxf(b, smw[i]); }
    scales[0] = a;
    scales[1] = b;
  }
}

// Quantize: q = rint(a * invnorm_row * 127/scale) -> int8, packed 4/thread.
__global__ __launch_bounds__(256) void quant_kernel(
    const float* __restrict__ a, const float* __restrict__ invnorm,
    const float* __restrict__ scale, unsigned int* __restrict__ qout) {
  const int idx = blockIdx.x * 256 + threadIdx.x;     // one float4 per thread
  const float s = 127.0f / scale[0];
  const float4 v = ((const float4*)a)[idx];
  const int row = idx >> 8;                           // 256 float4 per row
  const float f = invnorm[row] * s;
  int q0 = (int)rintf(v.x * f);
  int q1 = (int)rintf(v.y * f);
  int q2 = (int)rintf(v.z * f);
  int q3 = (int)rintf(v.w * f);
  qout[idx] = (unsigned)(q0 & 0xff) | ((unsigned)(q1 & 0xff) << 8) |
              ((unsigned)(q2 & 0xff) << 16) | ((unsigned)(q3 & 0xff) << 24);
}

// int8 GEMM: out[m,n] = 1 - (qx[m,:] . qw[n,:]) * cs
// 128x128 tile, 4 waves (2x2 of 64x64), BK=64, mfma_i32_16x16x64_i8.
__global__ __launch_bounds__(256) void gemm_i8_kernel(
    const char* __restrict__ qx, const char* __restrict__ qw,
    const float* __restrict__ sx, const float* __restrict__ sw,
    float* __restrict__ out) {
  __shared__ char As[8192];
  __shared__ char Bs[8192];
  const int t = threadIdx.x;
  const int wave = t >> 6, lane = t & 63;
  const int wr = wave >> 1, wc = wave & 1;
  const int rowBase = blockIdx.y * 128;
  const int colBase = blockIdx.x * 128;

  i32x4 acc[4][4] = {};

  const int ko = lane >> 4, rl = lane & 15;

#pragma unroll 1
  for (int ks = 0; ks < 16; ++ks) {
    __syncthreads();  // previous compute done; safe to overwrite tiles
    const int k0 = ks * 64;
#pragma unroll
    for (int is = 0; is < 2; ++is) {
      const int ci = is * 256 + t;          // chunk index 0..511
      const int cko = ci >> 7, cr = ci & 127;
      const size_t goffA = (size_t)(rowBase + cr) * D_COLS + k0 + cko * 16;
      const size_t goffB = (size_t)(colBase + cr) * D_COLS + k0 + cko * 16;
      char* ldsA = As + is * 4096 + wave * 1024;  // wave-uniform base
      char* ldsB = Bs + is * 4096 + wave * 1024;
      gload_lds16(qx + goffA, ldsA);
      gload_lds16(qw + goffB, ldsB);
    }
    __syncthreads();  // drains vmcnt before barrier => tiles ready

    i32x4 af[4], bf[4];
#pragma unroll
    for (int m = 0; m < 4; ++m)
      af[m] = *(const i32x4*)(As + ko * 2048 + (wr * 64 + m * 16 + rl) * 16);
#pragma unroll
    for (int n = 0; n < 4; ++n)
      bf[n] = *(const i32x4*)(Bs + ko * 2048 + (wc * 64 + n * 16 + rl) * 16);
#pragma unroll
    for (int m = 0; m < 4; ++m)
#pragma unroll
      for (int n = 0; n < 4; ++n)
        acc[m][n] = __builtin_amdgcn_mfma_i32_16x16x64_i8(af[m], bf[n], acc[m][n], 0, 0, 0);
  }

  const float cs = sx[0] * sw[0] * (1.0f / 16129.0f);  // (sx/127)*(sw/127)
#pragma unroll
  for (int m = 0; m < 4; ++m) {
    const int row = rowBase + wr * 64 + m * 16 + (lane >> 4) * 4;
#pragma unroll
    for (int n = 0; n < 4; ++n) {
      const int col = colBase + wc * 64 + n * 16 + (lane & 15);
#pragma unroll
      for (int j = 0; j < 4; ++j)
        out[(size_t)(row + j) * N_ROWS + col] = 1.0f - (float)acc[m][n][j] * cs;
    }
  }
}

extern "C" void kernel_launch(void* const* d_in, const int* in_sizes, int n_in,
                              void* d_out, int out_size, void* d_ws, size_t ws_size,
                              hipStream_t stream) {
  const float* x = (const float*)d_in[0];   // [4096, 1024]
  const float* w = (const float*)d_in[1];   // [8192, 1024]
  float* out = (float*)d_out;               // [4096, 8192]

  char* ws = (char*)d_ws;
  char* qx = ws;                                        // 4 MB int8
  char* qw = ws + (size_t)M_ROWS * D_COLS;              // 8 MB int8
  float* invnorm = (float*)(ws + (size_t)(M_ROWS + N_ROWS) * D_COLS);  // [12288]
  float* rmax = invnorm + (M_ROWS + N_ROWS);            // [12288]
  float* scales = rmax + (M_ROWS + N_ROWS);             // [0]=sx, [1]=sw

  rownorm_kernel<<<M_ROWS + N_ROWS, 256, 0, stream>>>(x, w, invnorm, rmax);
  scale_reduce_kernel<<<1, 1024, 0, stream>>>(rmax, scales);

  quant_kernel<<<M_ROWS * (D_COLS / 4) / 256, 256, 0, stream>>>(
      x, invnorm, &scales[0], (unsigned int*)qx);
  quant_kernel<<<N_ROWS * (D_COLS / 4) / 256, 256, 0, stream>>>(
      w, invnorm + M_ROWS, &scales[1], (unsigned int*)qw);

  dim3 grid(N_ROWS / 128, M_ROWS / 128);  // (64, 32)
  gemm_i8_kernel<<<grid, 256, 0, stream>>>(qx, qw, &scales[0], &scales[1], out);
}